// Round 11
// baseline (1183.036 us; speedup 1.0000x reference)
//
#include <hip/hip_runtime.h>
#include <hip/hip_bf16.h>
#include <hip/hip_cooperative_groups.h>
namespace cg = cooperative_groups;

typedef unsigned short u16;
typedef unsigned int u32;

#define WIDTH 64
#define KERW 4096   // 64*64
#define K2DIM 128
#define DEPTH 4
#define MEB 16      // edges per mlp12 block

typedef __attribute__((ext_vector_type(8))) short short8;
typedef __attribute__((ext_vector_type(4))) float f32x4;
typedef __attribute__((ext_vector_type(4))) u32 u32x4;

__device__ __forceinline__ u16 f2bf(float f) {
    union { float f; u32 u; } v; v.f = f;
    u32 r = v.u + 0x7FFFu + ((v.u >> 16) & 1u);
    return (u16)(r >> 16);
}
__device__ __forceinline__ float bflo(u32 u) { return __uint_as_float(u << 16); }
__device__ __forceinline__ float bfhi(u32 u) { return __uint_as_float(u & 0xFFFF0000u); }

// Stored W layout: pos o*64 + sig(i) holds W[e][i][o], sig(i) = (i&15)*4 + (i>>4).
// h2 / Bp fragment-packed: idx_u16(row,k) = (row>>4)*2048 + (k>>5)*512
//   + ((row&15) + 16*((k>>3)&3))*8 + (k&7)   => GEMM loads are 1KB wave-contiguous.
// W normal caching (197MB fits 256MB L3; msg reads from Infinity Cache).
// All 4 msg+combine layers + head run in ONE cooperative kernel (grid.sync).

// ---------------- pre_k: count | fc1 | prep_b(set1) | prep_b(set2) | rootsum ----------------
__global__ void pre_k(const int* __restrict__ dst1, int E,
                      const int* __restrict__ dst2, int Eb,
                      float* __restrict__ cnt, int N,
                      const float* __restrict__ x, const float* __restrict__ fc1w,
                      const float* __restrict__ fc1b, float* __restrict__ x0,
                      const float* __restrict__ w3a, const float* __restrict__ b3a,
                      u16* __restrict__ Bp1, float* __restrict__ b3p1,
                      const float* __restrict__ w3b, const float* __restrict__ b3b,
                      u16* __restrict__ Bp2, float* __restrict__ b3p2,
                      const float* __restrict__ root1, const float* __restrict__ root2,
                      float* __restrict__ rootsum,
                      const float* __restrict__ bias1, const float* __restrict__ bias2,
                      float* __restrict__ bsum,
                      int nbC, int nbF) {
    int bid = blockIdx.x, t = threadIdx.x;
    if (bid < nbC) {
        int i = bid * 256 + t;
        if (i < E) atomicAdd(&cnt[dst1[i]], 1.0f);
        else if (i < E + Eb) atomicAdd(&cnt[N + dst2[i - E]], 1.0f);
        return;
    }
    bid -= nbC;
    if (bid < nbF) {
        int idx = bid * 256 + t;
        if (idx < N * WIDTH) {
            int n = idx >> 6, j = idx & 63;
            x0[idx] = fc1w[j] * x[n] + fc1b[j];
        }
        return;
    }
    bid -= nbF;
    if (bid < 4096) {
        const float* w3 = w3a; const float* b3 = b3a;
        u16* Bp = Bp1; float* b3p = b3p1;
        if (bid >= 2048) { bid -= 2048; w3 = w3b; b3 = b3b; Bp = Bp2; b3p = b3p2; }
        int idx = bid * 256 + t;   // 4096*128
        int c = idx >> 7, k = idx & 127;
        int i = c & 63, o = c >> 6;
        int pr = (i << 6) | o;
        size_t w = (size_t)(c >> 4) * 2048 + (k >> 5) * 512
                 + (((c & 15) + 16 * ((k >> 3) & 3)) << 3) + (k & 7);
        Bp[w] = f2bf(w3[(size_t)pr * 128 + k]);
        if (k == 0) b3p[(o << 6) | ((i & 15) << 2) | (i >> 4)] = b3[pr];
        return;
    }
    bid -= 4096;
    {
        int idx = bid * 256 + t;
        if (idx < 4096) rootsum[idx] = root1[idx] + root2[idx];
        if (idx < 64) bsum[idx] = bias1[idx] + bias2[idx];
    }
}

// ---------------- kernel-MLP layers 1+2 (both edge sets): -> h2 packed bf16 ----------------
__global__ __launch_bounds__(256) void mlp12_k(const float* __restrict__ eaA,
                                               const float* __restrict__ w1A, const float* __restrict__ b1A,
                                               const float* __restrict__ w2A, const float* __restrict__ b2A,
                                               u16* __restrict__ h2A, int EA, int nbA,
                                               const float* __restrict__ eaB,
                                               const float* __restrict__ w1B, const float* __restrict__ b1B,
                                               const float* __restrict__ w2B, const float* __restrict__ b2B,
                                               u16* __restrict__ h2B, int EB) {
    __shared__ u16   w2b[64 * 136];
    __shared__ float h1s[MEB * 65];
    __shared__ float w1s[64 * 6];
    __shared__ float b1s[64];
    __shared__ float b2s[128];
    __shared__ float eas[MEB * 6];
    int bid = blockIdx.x, t = threadIdx.x;
    const float *ea, *w1, *b1, *w2, *b2; u16* h2p; int E, e0;
    if (bid < nbA) { ea = eaA; w1 = w1A; b1 = b1A; w2 = w2A; b2 = b2A; h2p = h2A; E = EA; e0 = bid * MEB; }
    else { ea = eaB; w1 = w1B; b1 = b1B; w2 = w2B; b2 = b2B; h2p = h2B; E = EB; e0 = (bid - nbA) * MEB; }
    for (int i = t; i < 8192; i += 256)
        w2b[(i & 63) * 136 + (i >> 6)] = f2bf(w2[i]);
    for (int i = t; i < 384; i += 256) w1s[i] = w1[i];
    if (t < 64) b1s[t] = b1[t];
    if (t < 128) b2s[t] = b2[t];
    {
        int ne = min(MEB, E - e0) * 6;
        if (t < ne) eas[t] = ea[(size_t)e0 * 6 + t];
    }
    __syncthreads();
    for (int id = t; id < MEB * 64; id += 256) {
        int el = id >> 6, o = id & 63;
        float a = b1s[o];
        #pragma unroll
        for (int k = 0; k < 6; ++k) a += eas[el * 6 + k] * w1s[o * 6 + k];
        h1s[el * 65 + o] = fmaxf(a, 0.f);
    }
    __syncthreads();
    int el = t >> 4, og = (t & 15) * 8;
    int e = e0 + el;
    float acc[8];
    #pragma unroll
    for (int c = 0; c < 8; ++c) acc[c] = b2s[og + c];
    const float* h1r = &h1s[el * 65];
    #pragma unroll 8
    for (int j = 0; j < 64; ++j) {
        float hj = h1r[j];
        uint4 v = *(const uint4*)&w2b[j * 136 + og];
        acc[0] += bflo(v.x) * hj; acc[1] += bfhi(v.x) * hj;
        acc[2] += bflo(v.y) * hj; acc[3] += bfhi(v.y) * hj;
        acc[4] += bflo(v.z) * hj; acc[5] += bfhi(v.z) * hj;
        acc[6] += bflo(v.w) * hj; acc[7] += bfhi(v.w) * hj;
    }
    if (e < E) {
        size_t idx = (size_t)(e >> 4) * 2048 + (og >> 5) * 512
                   + (((e & 15) + 16 * ((og >> 3) & 3)) << 3);
        ushort4 p0, p1;
        p0.x = f2bf(fmaxf(acc[0], 0.f)); p0.y = f2bf(fmaxf(acc[1], 0.f));
        p0.z = f2bf(fmaxf(acc[2], 0.f)); p0.w = f2bf(fmaxf(acc[3], 0.f));
        p1.x = f2bf(fmaxf(acc[4], 0.f)); p1.y = f2bf(fmaxf(acc[5], 0.f));
        p1.z = f2bf(fmaxf(acc[6], 0.f)); p1.w = f2bf(fmaxf(acc[7], 0.f));
        *(ushort4*)(h2p + idx)     = p0;
        *(ushort4*)(h2p + idx + 4) = p1;
    }
}

// ---------------- big GEMM via MFMA, LDS-free, packed operands, both sets ----------------
__global__ __launch_bounds__(256, 4) void w3_mfma_k(const u16* __restrict__ h2A,
                                                    const u16* __restrict__ BpA,
                                                    const float* __restrict__ b3pA,
                                                    u16* __restrict__ WtA, int EA, int nEA, int g1,
                                                    const u16* __restrict__ h2B,
                                                    const u16* __restrict__ BpB,
                                                    const float* __restrict__ b3pB,
                                                    u16* __restrict__ WtB, int EB, int nEB) {
    int p = blockIdx.x;
    const u16 *h2p, *Bp; const float* b3p; u16* Wt; int E, nE;
    if (p < g1) { h2p = h2A; Bp = BpA; b3p = b3pA; Wt = WtA; E = EA; nE = nEA; }
    else { p -= g1; h2p = h2B; Bp = BpB; b3p = b3pB; Wt = WtB; E = EB; nE = nEB; }
    int xcd = p & 7, j = p >> 3;
    int t = (j >> 5) * 8 + xcd;
    if (t >= nE) return;
    int eb = t << 7, cb = (j & 31) << 7;

    int lane = threadIdx.x & 63, wv = threadIdx.x >> 6;
    int wr = (wv >> 1) << 6, wc = (wv & 1) << 6;
    int lr = lane & 15, lg = lane >> 4;

    const u16* abase = h2p + (size_t)((eb + wr) >> 4) * 2048 + lane * 8;
    const u16* bbase = Bp  + (size_t)((cb + wc) >> 4) * 2048 + lane * 8;

    f32x4 acc[4][4] = {};
    #pragma unroll
    for (int kk = 0; kk < 4; ++kk) {
        short8 af[4], bf[4];
        #pragma unroll
        for (int m = 0; m < 4; ++m) af[m] = *(const short8*)(abase + m * 2048 + kk * 512);
        #pragma unroll
        for (int n = 0; n < 4; ++n) bf[n] = *(const short8*)(bbase + n * 2048 + kk * 512);
        #pragma unroll
        for (int m = 0; m < 4; ++m)
            #pragma unroll
            for (int n = 0; n < 4; ++n)
                acc[m][n] = __builtin_amdgcn_mfma_f32_16x16x32_bf16(af[m], bf[n], acc[m][n], 0, 0, 0);
    }

    float4 bb4 = *(const float4*)(b3p + cb + wc + lr * 4);

    #pragma unroll
    for (int m = 0; m < 4; ++m) {
        #pragma unroll
        for (int r4 = 0; r4 < 4; ++r4) {
            int eg = eb + wr + m * 16 + lg * 4 + r4;
            if (eg < E) {
                ushort4 pk;
                pk.x = f2bf(acc[m][0][r4] + bb4.x);
                pk.y = f2bf(acc[m][1][r4] + bb4.y);
                pk.z = f2bf(acc[m][2][r4] + bb4.z);
                pk.w = f2bf(acc[m][3][r4] + bb4.w);
                *(ushort4*)(Wt + (size_t)eg * KERW + cb + wc + lr * 4) = pk;
            }
        }
    }
}

// ---------------- cooperative: 4 x (msg + combine) + head ----------------
__global__ __launch_bounds__(256, 8) void layers_k(
    const float* __restrict__ x0, float* __restrict__ hA, float* __restrict__ hB,
    float* __restrict__ sbuf, const float* __restrict__ cnt,
    const u16* __restrict__ W1, const int* __restrict__ src1, const int* __restrict__ dst1,
    int E, int nbM1,
    const u16* __restrict__ W2, const int* __restrict__ src2, const int* __restrict__ dst2,
    int Eb, int nbM2,
    const float* __restrict__ rootsum, const float* __restrict__ bsumg,
    const float* __restrict__ fc2w, const float* __restrict__ fc2b,
    const float* __restrict__ fc3w, const float* __restrict__ fc3b,
    float* __restrict__ out, int N, int nbC, int nbH)
{
    __shared__ float rs[4096];    // rootsum staged once for all 4 layers; reused as bf16 fc2 in head
    __shared__ float hs[4][64];   // msg h staging (per-wave rows)
    __shared__ float hr[4][64];   // combine h staging / head hr (first 2 rows)
    __shared__ float red[2][128]; // head reduction
    int t = threadIdx.x;
    int nb = gridDim.x;
    for (int j = t; j < 4096; j += 256) rs[j] = rootsum[j];
    __syncthreads();
    cg::grid_group grid = cg::this_grid();

    int w = t >> 6, lane = t & 63;
    int o = t & 63;
    const float* hcur = x0;
    float* bufs[2] = { hA, hB };

    for (int l = 0; l < DEPTH; ++l) {
        float* hnext = bufs[l & 1];
        // ---- msg phase (grid-stride over edge groups; per-wave hs rows, no barrier) ----
        for (int vb = blockIdx.x; vb < nbM1 + nbM2; vb += nb) {
            const u16* Wt; const int *src, *dst; float* s; int E_, e;
            if (vb < nbM1) { Wt = W1; src = src1; dst = dst1; s = sbuf; E_ = E; e = vb * 4 + w; }
            else { Wt = W2; src = src2; dst = dst2; s = sbuf + (size_t)N * 64; E_ = Eb; e = (vb - nbM1) * 4 + w; }
            bool valid = e < E_;
            int ec = valid ? e : 0;
            int sv = src[ec];
            hs[w][((lane & 15) << 2) | (lane >> 4)] = hcur[(size_t)sv * 64 + lane]; // sig-permuted
            float4 h0 = *(const float4*)&hs[w][(lane & 7) * 8];
            float4 h1 = *(const float4*)&hs[w][(lane & 7) * 8 + 4];
            const char* base = (const char*)(Wt + (size_t)ec * KERW) + lane * 16;
            float acc[8];
            #pragma unroll
            for (int jj = 0; jj < 8; ++jj) {
                u32x4 v = *(const u32x4*)(base + jj * 1024);
                float a;
                a  = bflo(v[0]) * h0.x; a += bfhi(v[0]) * h0.y;
                a += bflo(v[1]) * h0.z; a += bfhi(v[1]) * h0.w;
                a += bflo(v[2]) * h1.x; a += bfhi(v[2]) * h1.y;
                a += bflo(v[3]) * h1.z; a += bfhi(v[3]) * h1.w;
                acc[jj] = a;
            }
            #pragma unroll
            for (int jj = 0; jj < 8; ++jj) {
                acc[jj] += __shfl_xor(acc[jj], 1, 64);
                acc[jj] += __shfl_xor(acc[jj], 2, 64);
                acc[jj] += __shfl_xor(acc[jj], 4, 64);
            }
            int c = lane & 7;
            float val = acc[0];
            #pragma unroll
            for (int jj = 1; jj < 8; ++jj) val = (c == jj) ? acc[jj] : val;
            if (valid) atomicAdd(&s[(size_t)dst[ec] * 64 + ((c << 3) | (lane >> 3))], val);
        }
        grid.sync();
        // ---- combine phase ----
        {
            float bsum = bsumg[o];
            for (int vb = blockIdx.x; vb < nbC; vb += nb) {
                #pragma unroll
                for (int g = 0; g < 4; ++g) {
                    int n = vb * 16 + g * 4 + w;
                    bool valid = n < N;
                    int nc = valid ? n : 0;
                    hr[w][o] = hcur[(size_t)nc * 64 + o];   // wave-private row, lockstep
                    float inv1 = 1.0f / fmaxf(cnt[nc], 1.0f);
                    float inv2 = 1.0f / fmaxf(cnt[N + nc], 1.0f);
                    float acc = sbuf[(size_t)nc * 64 + o] * inv1
                              + sbuf[(size_t)(N + nc) * 64 + o] * inv2
                              + bsum;
                    if (valid) {   // re-zero for next layer
                        sbuf[(size_t)nc * 64 + o] = 0.f;
                        sbuf[(size_t)(N + nc) * 64 + o] = 0.f;
                    }
                    #pragma unroll 8
                    for (int i = 0; i < 64; ++i) acc += hr[w][i] * rs[i * 64 + o];
                    if (valid) hnext[(size_t)n * 64 + o] = fmaxf(acc, 0.f) + x0[(size_t)n * 64 + o];
                }
            }
        }
        grid.sync();
        hcur = hnext;
    }

    // ---- head phase: stage fc2w bf16 TRANSPOSED into rs (as u16), 2 nodes/block-iter ----
    u16* fc2s = (u16*)rs;
    __syncthreads();
    for (int idx = t; idx < 8192; idx += 256) {
        int r = idx >> 6, i = idx & 63;
        fc2s[i * 128 + r] = f2bf(fc2w[idx]);
    }
    __syncthreads();
    int half = t >> 7, tt = t & 127;
    for (int vb = blockIdx.x; vb < nbH; vb += nb) {
        int n = vb * 2 + half;
        int nc = n < N ? n : 0;
        if (tt < 64) hr[half][tt] = hcur[(size_t)nc * 64 + tt];
        __syncthreads();
        float a = fc2b[tt];
        #pragma unroll 8
        for (int i = 0; i < 64; ++i) a += hr[half][i] * bflo((u32)fc2s[i * 128 + tt]);
        red[half][tt] = fmaxf(a, 0.f) * fc3w[tt];
        __syncthreads();
        if (tt < 64) {
            float v = red[half][tt] + red[half][tt + 64];
            for (int off = 32; off; off >>= 1) v += __shfl_down(v, off);
            if (tt == 0 && n < N) out[n] = v + fc3b[0];
        }
        __syncthreads();
    }
}

extern "C" void kernel_launch(void* const* d_in, const int* in_sizes, int n_in,
                              void* d_out, int out_size, void* d_ws, size_t ws_size,
                              hipStream_t stream) {
    const float* x    = (const float*)d_in[0];
    const int*   ei   = (const int*)d_in[1];
    const float* ea   = (const float*)d_in[2];
    const int*   eib  = (const int*)d_in[3];
    const float* eab  = (const float*)d_in[4];
    const float* fc1w = (const float*)d_in[5];
    const float* fc1b = (const float*)d_in[6];
    const float* fc2w = (const float*)d_in[7];
    const float* fc2b = (const float*)d_in[8];
    const float* fc3w = (const float*)d_in[9];
    const float* fc3b = (const float*)d_in[10];
    const float* k1w1 = (const float*)d_in[11];
    const float* k1b1 = (const float*)d_in[12];
    const float* k1w2 = (const float*)d_in[13];
    const float* k1b2 = (const float*)d_in[14];
    const float* k1w3 = (const float*)d_in[15];
    const float* k1b3 = (const float*)d_in[16];
    const float* root1 = (const float*)d_in[17];
    const float* bias1 = (const float*)d_in[18];
    const float* k2w1 = (const float*)d_in[19];
    const float* k2b1 = (const float*)d_in[20];
    const float* k2w2 = (const float*)d_in[21];
    const float* k2b2 = (const float*)d_in[22];
    const float* k2w3 = (const float*)d_in[23];
    const float* k2b3 = (const float*)d_in[24];
    const float* root2 = (const float*)d_in[25];
    const float* bias2 = (const float*)d_in[26];
    float* out = (float*)d_out;

    const int N  = in_sizes[0];
    const int E  = in_sizes[2] / 6;
    const int Eb = in_sizes[4] / 6;

    const int nE1 = (E + 127) / 128,  nE1p = ((nE1 + 7) / 8) * 8;
    const int nE2 = (Eb + 127) / 128, nE2p = ((nE2 + 7) / 8) * 8;

    // ---- workspace carve (256B aligned) ----
    char* p = (char*)d_ws;
    auto alloc = [&](size_t bytes) {
        char* r = p;
        p += (bytes + 255) & ~(size_t)255;
        return (void*)r;
    };
    float* x0   = (float*)alloc((size_t)N * 64 * 4);
    float* hA   = (float*)alloc((size_t)N * 64 * 4);
    float* hB   = (float*)alloc((size_t)N * 64 * 4);
    float* sbuf = (float*)alloc((size_t)2 * N * 64 * 4);   // s1 | s2
    float* cnt  = (float*)alloc((size_t)2 * N * 4);        // cnt1 | cnt2
    char*  zero0 = (char*)sbuf;
    size_t zero0Bytes = (size_t)((char*)cnt - (char*)sbuf) + (size_t)2 * N * 4;
    size_t h2aBytes = (size_t)nE1p * 128 * K2DIM * 2;      // packed, padded rows
    size_t h2bBytes = (size_t)nE2p * 128 * K2DIM * 2;
    u16*   h2a  = (u16*)alloc(h2aBytes);
    u16*   h2b  = (u16*)alloc(h2bBytes);
    size_t zero1Bytes = (size_t)((char*)h2b - (char*)h2a) + h2bBytes;
    u16*   Bp1  = (u16*)alloc((size_t)KERW * K2DIM * 2);
    u16*   Bp2  = (u16*)alloc((size_t)KERW * K2DIM * 2);
    float* b3p1 = (float*)alloc((size_t)KERW * 4);
    float* b3p2 = (float*)alloc((size_t)KERW * 4);
    float* rootsum = (float*)alloc((size_t)KERW * 4);
    float* bsum = (float*)alloc((size_t)64 * 4);
    u16*   W1   = (u16*)alloc((size_t)E * KERW * 2);
    u16*   W2   = (u16*)alloc((size_t)Eb * KERW * 2);
    (void)ws_size;

    const int* src1 = ei;       const int* dst1 = ei + E;
    const int* src2 = eib;      const int* dst2 = eib + Eb;

    // ---- precompute phase ----
    hipMemsetAsync(zero0, 0, zero0Bytes, stream);           // sbuf + cnt
    hipMemsetAsync(h2a, 0, zero1Bytes, stream);             // h2a + h2b (pad rows -> zeros)

    {
        int nbA = (E + MEB - 1) / MEB, nbB = (Eb + MEB - 1) / MEB;
        mlp12_k<<<nbA + nbB, 256, 0, stream>>>(ea, k1w1, k1b1, k1w2, k1b2, h2a, E, nbA,
                                               eab, k2w1, k2b1, k2w2, k2b2, h2b, Eb);
    }
    {
        int nbC = (E + Eb + 255) / 256;
        int nbF = (N * WIDTH + 255) / 256;
        pre_k<<<nbC + nbF + 4096 + 16, 256, 0, stream>>>(dst1, E, dst2, Eb, cnt, N,
                                                         x, fc1w, fc1b, x0,
                                                         k1w3, k1b3, Bp1, b3p1,
                                                         k2w3, k2b3, Bp2, b3p2,
                                                         root1, root2, rootsum,
                                                         bias1, bias2, bsum,
                                                         nbC, nbF);
    }
    {
        int g1 = nE1p * 32, g2 = nE2p * 32;
        w3_mfma_k<<<g1 + g2, 256, 0, stream>>>(h2a, Bp1, b3p1, W1, E, nE1, g1,
                                               h2b, Bp2, b3p2, W2, Eb, nE2);
    }

    // ---- cooperative layer loop + head ----
    {
        int occ = 0;
        hipOccupancyMaxActiveBlocksPerMultiprocessor(&occ, layers_k, 256, 0);
        if (occ < 1) occ = 1;
        int nblk = occ * 256;               // 256 CUs on MI355X
        int nbM1 = (E + 3) / 4, nbM2 = (Eb + 3) / 4;
        int E_ = E, Eb_ = Eb, N_ = N;
        int nbC_ = (N + 15) / 16, nbH_ = (N + 1) / 2;
        void* kargs[] = {
            (void*)&x0, (void*)&hA, (void*)&hB, (void*)&sbuf, (void*)&cnt,
            (void*)&W1, (void*)&src1, (void*)&dst1, (void*)&E_, (void*)&nbM1,
            (void*)&W2, (void*)&src2, (void*)&dst2, (void*)&Eb_, (void*)&nbM2,
            (void*)&rootsum, (void*)&bsum, (void*)&fc2w, (void*)&fc2b,
            (void*)&fc3w, (void*)&fc3b, (void*)&out, (void*)&N_, (void*)&nbC_, (void*)&nbH_
        };
        hipLaunchCooperativeKernel(layers_k, dim3(nblk), dim3(256), kargs, 0, stream);
    }
}

// Round 12
// 269.271 us; speedup vs baseline: 4.3935x; 4.3935x over previous
//
#include <hip/hip_runtime.h>
#include <hip/hip_bf16.h>

typedef unsigned short u16;
typedef unsigned int u32;

#define WIDTH 64
#define KERW 4096   // 64*64
#define K2DIM 128
#define DEPTH 4
#define MEB 16      // edges per mlp block
#define HNB 16      // nodes per head block

typedef __attribute__((ext_vector_type(8))) short short8;
typedef __attribute__((ext_vector_type(4))) float f32x4;
typedef __attribute__((ext_vector_type(4))) u32 u32x4;

__device__ __forceinline__ u16 f2bf(float f) {
    union { float f; u32 u; } v; v.f = f;
    u32 r = v.u + 0x7FFFu + ((v.u >> 16) & 1u);
    return (u16)(r >> 16);
}
__device__ __forceinline__ float bflo(u32 u) { return __uint_as_float(u << 16); }
__device__ __forceinline__ float bfhi(u32 u) { return __uint_as_float(u & 0xFFFF0000u); }

// Stored W layout: pos o*64 + sig(i) holds W[e][i][o], sig(i) = (i&15)*4 + (i>>4).
// h2 / Bp fragment-packed: idx_u16(row,k) = (row>>4)*2048 + (k>>5)*512
//   + ((row&15) + 16*((k>>3)&3))*8 + (k&7)   => GEMM loads are 1KB wave-contiguous.
// W normal caching (197MB fits 256MB L3; msg reads mostly from Infinity Cache).
// NO cooperative/grid.sync (R10 lesson: grid.sync at scale costs 100s of µs).

// ---------------- mlp block body (kernel-MLP layers 1+2 -> h2 packed bf16) ----------------
__device__ __forceinline__ void mlp_block(const float* __restrict__ ea,
                                          const float* __restrict__ w1, const float* __restrict__ b1,
                                          const float* __restrict__ w2, const float* __restrict__ b2,
                                          u16* __restrict__ h2p, int E, int e0, int t) {
    __shared__ u16   w2b[64 * 136];   // [j][o], pad 136
    __shared__ float h1s[MEB * 65];
    __shared__ float w1s[64 * 6];
    __shared__ float b1s[64];
    __shared__ float b2s[128];
    __shared__ float eas[MEB * 6];
    for (int i = t; i < 8192; i += 256)          // w2[o*64+j] -> w2b[j*136+o]
        w2b[(i & 63) * 136 + (i >> 6)] = f2bf(w2[i]);
    for (int i = t; i < 384; i += 256) w1s[i] = w1[i];
    if (t < 64) b1s[t] = b1[t];
    if (t < 128) b2s[t] = b2[t];
    {
        int ne = min(MEB, E - e0) * 6;
        if (t < ne) eas[t] = ea[(size_t)e0 * 6 + t];
    }
    __syncthreads();
    for (int id = t; id < MEB * 64; id += 256) {
        int el = id >> 6, o = id & 63;
        float a = b1s[o];
        #pragma unroll
        for (int k = 0; k < 6; ++k) a += eas[el * 6 + k] * w1s[o * 6 + k];
        h1s[el * 65 + o] = fmaxf(a, 0.f);
    }
    __syncthreads();
    int el = t >> 4, og = (t & 15) * 8;
    int e = e0 + el;
    float acc[8];
    #pragma unroll
    for (int c = 0; c < 8; ++c) acc[c] = b2s[og + c];
    const float* h1r = &h1s[el * 65];
    #pragma unroll 8
    for (int j = 0; j < 64; ++j) {
        float hj = h1r[j];
        uint4 v = *(const uint4*)&w2b[j * 136 + og];
        acc[0] += bflo(v.x) * hj; acc[1] += bfhi(v.x) * hj;
        acc[2] += bflo(v.y) * hj; acc[3] += bfhi(v.y) * hj;
        acc[4] += bflo(v.z) * hj; acc[5] += bfhi(v.z) * hj;
        acc[6] += bflo(v.w) * hj; acc[7] += bfhi(v.w) * hj;
    }
    if (e < E) {
        size_t idx = (size_t)(e >> 4) * 2048 + (og >> 5) * 512
                   + (((e & 15) + 16 * ((og >> 3) & 3)) << 3);
        ushort4 p0, p1;
        p0.x = f2bf(fmaxf(acc[0], 0.f)); p0.y = f2bf(fmaxf(acc[1], 0.f));
        p0.z = f2bf(fmaxf(acc[2], 0.f)); p0.w = f2bf(fmaxf(acc[3], 0.f));
        p1.x = f2bf(fmaxf(acc[4], 0.f)); p1.y = f2bf(fmaxf(acc[5], 0.f));
        p1.z = f2bf(fmaxf(acc[6], 0.f)); p1.w = f2bf(fmaxf(acc[7], 0.f));
        *(ushort4*)(h2p + idx)     = p0;
        *(ushort4*)(h2p + idx + 4) = p1;
    }
}

// ---------------- pre_k: mlpA | mlpB | count | fc1 | prep_b x2 | rootsum ----------------
__global__ __launch_bounds__(256) void pre_k(
    const float* __restrict__ eaA, const float* __restrict__ w1A, const float* __restrict__ b1A,
    const float* __restrict__ w2A, const float* __restrict__ b2A, u16* __restrict__ h2A, int nbA,
    const float* __restrict__ eaB, const float* __restrict__ w1B, const float* __restrict__ b1B,
    const float* __restrict__ w2B, const float* __restrict__ b2B, u16* __restrict__ h2B, int nbB,
    const int* __restrict__ dst1, int E, const int* __restrict__ dst2, int Eb,
    float* __restrict__ cnt, int N,
    const float* __restrict__ x, const float* __restrict__ fc1w,
    const float* __restrict__ fc1b, float* __restrict__ x0,
    const float* __restrict__ w3a, const float* __restrict__ b3a,
    u16* __restrict__ Bp1, float* __restrict__ b3p1,
    const float* __restrict__ w3b, const float* __restrict__ b3b,
    u16* __restrict__ Bp2, float* __restrict__ b3p2,
    const float* __restrict__ root1, const float* __restrict__ root2,
    float* __restrict__ rootsum,
    const float* __restrict__ bias1, const float* __restrict__ bias2,
    float* __restrict__ bsum,
    int nbC, int nbF)
{
    int bid = blockIdx.x, t = threadIdx.x;
    if (bid < nbA) { mlp_block(eaA, w1A, b1A, w2A, b2A, h2A, E, bid * MEB, t); return; }
    bid -= nbA;
    if (bid < nbB) { mlp_block(eaB, w1B, b1B, w2B, b2B, h2B, Eb, bid * MEB, t); return; }
    bid -= nbB;
    if (bid < nbC) {
        int i = bid * 256 + t;
        if (i < E) atomicAdd(&cnt[dst1[i]], 1.0f);
        else if (i < E + Eb) atomicAdd(&cnt[N + dst2[i - E]], 1.0f);
        return;
    }
    bid -= nbC;
    if (bid < nbF) {
        int idx = bid * 256 + t;
        if (idx < N * WIDTH) {
            int n = idx >> 6, j = idx & 63;
            x0[idx] = fc1w[j] * x[n] + fc1b[j];
        }
        return;
    }
    bid -= nbF;
    if (bid < 4096) {
        const float* w3 = w3a; const float* b3 = b3a;
        u16* Bp = Bp1; float* b3p = b3p1;
        if (bid >= 2048) { bid -= 2048; w3 = w3b; b3 = b3b; Bp = Bp2; b3p = b3p2; }
        int idx = bid * 256 + t;   // 4096*128
        int c = idx >> 7, k = idx & 127;
        int i = c & 63, o = c >> 6;
        int pr = (i << 6) | o;
        size_t w = (size_t)(c >> 4) * 2048 + (k >> 5) * 512
                 + (((c & 15) + 16 * ((k >> 3) & 3)) << 3) + (k & 7);
        Bp[w] = f2bf(w3[(size_t)pr * 128 + k]);
        if (k == 0) b3p[(o << 6) | ((i & 15) << 2) | (i >> 4)] = b3[pr];
        return;
    }
    // rootsum + bsum (single block)
    for (int idx = t; idx < 4096; idx += 256) rootsum[idx] = root1[idx] + root2[idx];
    if (t < 64) bsum[t] = bias1[t] + bias2[t];
}

// ---------------- big GEMM via MFMA, LDS-free, packed operands, both sets ----------------
__global__ __launch_bounds__(256, 4) void w3_mfma_k(const u16* __restrict__ h2A,
                                                    const u16* __restrict__ BpA,
                                                    const float* __restrict__ b3pA,
                                                    u16* __restrict__ WtA, int EA, int nEA, int g1,
                                                    const u16* __restrict__ h2B,
                                                    const u16* __restrict__ BpB,
                                                    const float* __restrict__ b3pB,
                                                    u16* __restrict__ WtB, int EB, int nEB) {
    int p = blockIdx.x;
    const u16 *h2p, *Bp; const float* b3p; u16* Wt; int E, nE;
    if (p < g1) { h2p = h2A; Bp = BpA; b3p = b3pA; Wt = WtA; E = EA; nE = nEA; }
    else { p -= g1; h2p = h2B; Bp = BpB; b3p = b3pB; Wt = WtB; E = EB; nE = nEB; }
    int xcd = p & 7, j = p >> 3;
    int t = (j >> 5) * 8 + xcd;
    if (t >= nE) return;
    int eb = t << 7, cb = (j & 31) << 7;

    int lane = threadIdx.x & 63, wv = threadIdx.x >> 6;
    int wr = (wv >> 1) << 6, wc = (wv & 1) << 6;
    int lr = lane & 15, lg = lane >> 4;

    const u16* abase = h2p + (size_t)((eb + wr) >> 4) * 2048 + lane * 8;
    const u16* bbase = Bp  + (size_t)((cb + wc) >> 4) * 2048 + lane * 8;

    f32x4 acc[4][4] = {};
    #pragma unroll
    for (int kk = 0; kk < 4; ++kk) {
        short8 af[4], bf[4];
        #pragma unroll
        for (int m = 0; m < 4; ++m) af[m] = *(const short8*)(abase + m * 2048 + kk * 512);
        #pragma unroll
        for (int n = 0; n < 4; ++n) bf[n] = *(const short8*)(bbase + n * 2048 + kk * 512);
        #pragma unroll
        for (int m = 0; m < 4; ++m)
            #pragma unroll
            for (int n = 0; n < 4; ++n)
                acc[m][n] = __builtin_amdgcn_mfma_f32_16x16x32_bf16(af[m], bf[n], acc[m][n], 0, 0, 0);
    }

    float4 bb4 = *(const float4*)(b3p + cb + wc + lr * 4);

    #pragma unroll
    for (int m = 0; m < 4; ++m) {
        #pragma unroll
        for (int r4 = 0; r4 < 4; ++r4) {
            int eg = eb + wr + m * 16 + lg * 4 + r4;
            if (eg < E) {
                ushort4 pk;
                pk.x = f2bf(acc[m][0][r4] + bb4.x);
                pk.y = f2bf(acc[m][1][r4] + bb4.y);
                pk.z = f2bf(acc[m][2][r4] + bb4.z);
                pk.w = f2bf(acc[m][3][r4] + bb4.w);
                *(ushort4*)(Wt + (size_t)eg * KERW + cb + wc + lr * 4) = pk;
            }
        }
    }
}

// ---------------- message + scatter-add (both edge sets) ----------------
__global__ __launch_bounds__(256) void msg_k(const float* __restrict__ h,
                                             const u16* __restrict__ WtA,
                                             const int* __restrict__ srcA, const int* __restrict__ dstA,
                                             float* __restrict__ sA, int EA, int nbA,
                                             const u16* __restrict__ WtB,
                                             const int* __restrict__ srcB, const int* __restrict__ dstB,
                                             float* __restrict__ sB, int EB) {
    __shared__ float hs[4][64];
    int bid = blockIdx.x;
    int w = threadIdx.x >> 6, l = threadIdx.x & 63;
    const u16* Wt; const int *src, *dst; float* s; int E, e;
    if (bid < nbA) { Wt = WtA; src = srcA; dst = dstA; s = sA; E = EA; e = bid * 4 + w; }
    else { Wt = WtB; src = srcB; dst = dstB; s = sB; E = EB; e = (bid - nbA) * 4 + w; }
    bool valid = e < E;
    int ec = valid ? e : 0;
    int sv = src[ec];
    hs[w][((l & 15) << 2) | (l >> 4)] = h[(size_t)sv * 64 + l];   // sig-permuted staging
    __syncthreads();
    float4 h0 = *(const float4*)&hs[w][(l & 7) * 8];
    float4 h1 = *(const float4*)&hs[w][(l & 7) * 8 + 4];
    const char* base = (const char*)(Wt + (size_t)ec * KERW) + l * 16;
    float acc[8];
    #pragma unroll
    for (int jj = 0; jj < 8; ++jj) {
        u32x4 v = *(const u32x4*)(base + jj * 1024);
        float a;
        a  = bflo(v[0]) * h0.x; a += bfhi(v[0]) * h0.y;
        a += bflo(v[1]) * h0.z; a += bfhi(v[1]) * h0.w;
        a += bflo(v[2]) * h1.x; a += bfhi(v[2]) * h1.y;
        a += bflo(v[3]) * h1.z; a += bfhi(v[3]) * h1.w;
        acc[jj] = a;
    }
    #pragma unroll
    for (int jj = 0; jj < 8; ++jj) {
        acc[jj] += __shfl_xor(acc[jj], 1, 64);
        acc[jj] += __shfl_xor(acc[jj], 2, 64);
        acc[jj] += __shfl_xor(acc[jj], 4, 64);
    }
    int c = l & 7;
    float val = acc[0];
    #pragma unroll
    for (int jj = 1; jj < 8; ++jj) val = (c == jj) ? acc[jj] : val;   // static idx
    if (valid) atomicAdd(&s[(size_t)dst[ec] * 64 + ((c << 3) | (l >> 3))], val);
}

// ---------------- combine: mean + h@rootsum + bsum, relu, +x0; re-zero s ----------------
__global__ __launch_bounds__(256) void combine_k(const float* __restrict__ h,
                                                 float* __restrict__ s,         // [2][N][64]
                                                 const float* __restrict__ cnt, // [2][N]
                                                 const float* __restrict__ rootsum,
                                                 const float* __restrict__ bsumg,
                                                 const float* __restrict__ x0, float* __restrict__ hout, int N) {
    __shared__ float rs[64][64];
    __shared__ float hr[4][64];
    int t = threadIdx.x;
    for (int j = t; j < 4096; j += 256) rs[j >> 6][j & 63] = rootsum[j];
    int w = t >> 6, o = t & 63;
    float bsum = bsumg[o];
    __syncthreads();
    #pragma unroll
    for (int g = 0; g < 4; ++g) {
        int n = blockIdx.x * 16 + g * 4 + w;
        bool valid = n < N;
        int nc = valid ? n : 0;
        hr[w][o] = h[(size_t)nc * 64 + o];   // wave-private row, lockstep
        float inv1 = 1.0f / fmaxf(cnt[nc], 1.0f);
        float inv2 = 1.0f / fmaxf(cnt[N + nc], 1.0f);
        float acc = s[(size_t)nc * 64 + o] * inv1
                  + s[(size_t)(N + nc) * 64 + o] * inv2
                  + bsum;
        if (valid) {   // re-zero for next layer
            s[(size_t)nc * 64 + o] = 0.f;
            s[(size_t)(N + nc) * 64 + o] = 0.f;
        }
        #pragma unroll 8
        for (int i = 0; i < 64; ++i) acc += hr[w][i] * rs[i][o];
        if (valid) hout[(size_t)n * 64 + o] = fmaxf(acc, 0.f) + x0[(size_t)n * 64 + o];
    }
}

// ---------------- head: 16 nodes/block, fc2w staged bf16-transposed in LDS ----------------
__global__ __launch_bounds__(256) void head_k(const float* __restrict__ h,
                                              const float* __restrict__ fc2w, const float* __restrict__ fc2b,
                                              const float* __restrict__ fc3w, const float* __restrict__ fc3b,
                                              float* __restrict__ out, int N) {
    __shared__ u16 fc2s[64 * 132];   // [i][r], pad 132 (staging write 2-lane/bank, read stride-2B)
    __shared__ float hr[HNB][64];
    __shared__ float red[2][128];
    __shared__ float fb[128];
    __shared__ float f3[128];
    int t = threadIdx.x;
    int base = blockIdx.x * HNB;
    for (int idx = t; idx < 8192; idx += 256) {   // fc2w[r*64+i] -> fc2s[i*132+r]
        int r = idx >> 6, i = idx & 63;
        fc2s[i * 132 + r] = f2bf(fc2w[idx]);
    }
    if (t < 128) { fb[t] = fc2b[t]; f3[t] = fc3w[t]; }
    for (int id = t; id < HNB * 64; id += 256) {
        int g = id >> 6, i = id & 63;
        int n = base + g;
        hr[g][i] = h[(size_t)(n < N ? n : 0) * 64 + i];
    }
    __syncthreads();
    int half = t >> 7, tt = t & 127;
    for (int g = 0; g < HNB; g += 2) {
        int n = base + g + half;
        float a = fb[tt];
        const float* hh = hr[g + half];
        #pragma unroll 8
        for (int i = 0; i < 64; ++i) a += hh[i] * bflo((u32)fc2s[i * 132 + tt]);
        red[half][tt] = fmaxf(a, 0.f) * f3[tt];
        __syncthreads();
        if (tt < 64) {
            float v = red[half][tt] + red[half][tt + 64];
            for (int off = 32; off; off >>= 1) v += __shfl_down(v, off);
            if (tt == 0 && n < N) out[n] = v + fc3b[0];
        }
        __syncthreads();
    }
}

extern "C" void kernel_launch(void* const* d_in, const int* in_sizes, int n_in,
                              void* d_out, int out_size, void* d_ws, size_t ws_size,
                              hipStream_t stream) {
    const float* x    = (const float*)d_in[0];
    const int*   ei   = (const int*)d_in[1];
    const float* ea   = (const float*)d_in[2];
    const int*   eib  = (const int*)d_in[3];
    const float* eab  = (const float*)d_in[4];
    const float* fc1w = (const float*)d_in[5];
    const float* fc1b = (const float*)d_in[6];
    const float* fc2w = (const float*)d_in[7];
    const float* fc2b = (const float*)d_in[8];
    const float* fc3w = (const float*)d_in[9];
    const float* fc3b = (const float*)d_in[10];
    const float* k1w1 = (const float*)d_in[11];
    const float* k1b1 = (const float*)d_in[12];
    const float* k1w2 = (const float*)d_in[13];
    const float* k1b2 = (const float*)d_in[14];
    const float* k1w3 = (const float*)d_in[15];
    const float* k1b3 = (const float*)d_in[16];
    const float* root1 = (const float*)d_in[17];
    const float* bias1 = (const float*)d_in[18];
    const float* k2w1 = (const float*)d_in[19];
    const float* k2b1 = (const float*)d_in[20];
    const float* k2w2 = (const float*)d_in[21];
    const float* k2b2 = (const float*)d_in[22];
    const float* k2w3 = (const float*)d_in[23];
    const float* k2b3 = (const float*)d_in[24];
    const float* root2 = (const float*)d_in[25];
    const float* bias2 = (const float*)d_in[26];
    float* out = (float*)d_out;

    const int N  = in_sizes[0];
    const int E  = in_sizes[2] / 6;
    const int Eb = in_sizes[4] / 6;

    const int nE1 = (E + 127) / 128,  nE1p = ((nE1 + 7) / 8) * 8;
    const int nE2 = (Eb + 127) / 128, nE2p = ((nE2 + 7) / 8) * 8;

    // ---- workspace carve (256B aligned) ----
    char* p = (char*)d_ws;
    auto alloc = [&](size_t bytes) {
        char* r = p;
        p += (bytes + 255) & ~(size_t)255;
        return (void*)r;
    };
    float* x0   = (float*)alloc((size_t)N * 64 * 4);
    float* hA   = (float*)alloc((size_t)N * 64 * 4);
    float* hB   = (float*)alloc((size_t)N * 64 * 4);
    float* sbuf = (float*)alloc((size_t)2 * N * 64 * 4);   // s1 | s2
    float* cnt  = (float*)alloc((size_t)2 * N * 4);        // cnt1 | cnt2
    char*  zero0 = (char*)sbuf;
    size_t zero0Bytes = (size_t)((char*)cnt - (char*)sbuf) + (size_t)2 * N * 4;
    size_t h2aBytes = (size_t)nE1p * 128 * K2DIM * 2;      // packed, padded rows
    size_t h2bBytes = (size_t)nE2p * 128 * K2DIM * 2;
    u16*   h2a  = (u16*)alloc(h2aBytes);
    u16*   h2b  = (u16*)alloc(h2bBytes);
    size_t zero1Bytes = (size_t)((char*)h2b - (char*)h2a) + h2bBytes;
    u16*   Bp1  = (u16*)alloc((size_t)KERW * K2DIM * 2);
    u16*   Bp2  = (u16*)alloc((size_t)KERW * K2DIM * 2);
    float* b3p1 = (float*)alloc((size_t)KERW * 4);
    float* b3p2 = (float*)alloc((size_t)KERW * 4);
    float* rootsum = (float*)alloc((size_t)KERW * 4);
    float* bsum = (float*)alloc((size_t)64 * 4);
    u16*   W1   = (u16*)alloc((size_t)E * KERW * 2);
    u16*   W2   = (u16*)alloc((size_t)Eb * KERW * 2);
    (void)ws_size;

    const int* src1 = ei;       const int* dst1 = ei + E;
    const int* src2 = eib;      const int* dst2 = eib + Eb;

    // ---- precompute phase ----
    hipMemsetAsync(zero0, 0, zero0Bytes, stream);           // sbuf + cnt
    hipMemsetAsync(h2a, 0, zero1Bytes, stream);             // h2a + h2b (pad rows -> zeros)

    {
        int nbA = (E + MEB - 1) / MEB, nbB = (Eb + MEB - 1) / MEB;
        int nbC = (E + Eb + 255) / 256;
        int nbF = (N * WIDTH + 255) / 256;
        int grid = nbA + nbB + nbC + nbF + 4096 + 1;
        pre_k<<<grid, 256, 0, stream>>>(ea, k1w1, k1b1, k1w2, k1b2, h2a, nbA,
                                        eab, k2w1, k2b1, k2w2, k2b2, h2b, nbB,
                                        dst1, E, dst2, Eb, cnt, N,
                                        x, fc1w, fc1b, x0,
                                        k1w3, k1b3, Bp1, b3p1,
                                        k2w3, k2b3, Bp2, b3p2,
                                        root1, root2, rootsum,
                                        bias1, bias2, bsum,
                                        nbC, nbF);
    }
    {
        int g1 = nE1p * 32, g2 = nE2p * 32;
        w3_mfma_k<<<g1 + g2, 256, 0, stream>>>(h2a, Bp1, b3p1, W1, E, nE1, g1,
                                               h2b, Bp2, b3p2, W2, Eb, nE2);
    }

    // ---- 4 message-passing layers ----
    const float* hcur = x0;
    float* bufs[2] = { hA, hB };
    int nbM1 = (E + 3) / 4, nbM2 = (Eb + 3) / 4;
    for (int l = 0; l < DEPTH; ++l) {
        float* hnext = bufs[l & 1];
        msg_k<<<nbM1 + nbM2, 256, 0, stream>>>(hcur, W1, src1, dst1, sbuf, E, nbM1,
                                               W2, src2, dst2, sbuf + (size_t)N * 64, Eb);
        combine_k<<<(N + 15) / 16, 256, 0, stream>>>(hcur, sbuf, cnt, rootsum, bsum,
                                                     x0, hnext, N);
        hcur = hnext;
    }

    // ---- head ----
    head_k<<<(N + HNB - 1) / HNB, 256, 0, stream>>>(hcur, fc2w, fc2b, fc3w, fc3b, out, N);
}